// Round 6
// baseline (186.134 us; speedup 1.0000x reference)
//
#include <hip/hip_runtime.h>
#include <math.h>

#define RS2f 0.70710678118654752f

// ==================================================================
// Kernel 1: GEMM partials. P[z][m][n] = sum_{k in chunk z} A[m][k]W[n][k]
// M=1024,N=512,K=2048. Tile 128x128, BK=32, 8x8 micro-tile, float4
// stores. Register-prefetch pipeline: chunk k+1 global loads issued
// before chunk k compute (vmcnt hidden under 2048 FMAs/wave).
// ==================================================================
__global__ __launch_bounds__(256) void gemm_kernel(const float* __restrict__ A,
                                                   const float* __restrict__ W,
                                                   float* __restrict__ P) {
    __shared__ float As[32][128];
    __shared__ float Bs[32][128];
    const int tid = threadIdx.x;
    const int m0 = blockIdx.x * 128;
    const int n0 = blockIdx.y * 128;
    const int kchunk = 2048 / gridDim.z;
    const int nch = kchunk >> 5;
    const int kbase = blockIdx.z * kchunk;
    const int tm = tid >> 4, tn = tid & 15;
    const int srow = tid >> 1;           // 0..127
    const int scol = (tid & 1) * 16;     // 0 or 16
    float acc[8][8] = {};
    float4 a[4], w[4];
    {
        const float4* Ap = (const float4*)&A[(m0 + srow) * 2048 + kbase + scol];
        const float4* Wp = (const float4*)&W[(n0 + srow) * 2048 + kbase + scol];
        #pragma unroll
        for (int q = 0; q < 4; ++q) a[q] = Ap[q];
        #pragma unroll
        for (int q = 0; q < 4; ++q) w[q] = Wp[q];
    }
    for (int ch = 0; ch < nch; ++ch) {
        __syncthreads();
        #pragma unroll
        for (int q = 0; q < 4; ++q) {
            As[scol + 4*q + 0][srow] = a[q].x;
            As[scol + 4*q + 1][srow] = a[q].y;
            As[scol + 4*q + 2][srow] = a[q].z;
            As[scol + 4*q + 3][srow] = a[q].w;
            Bs[scol + 4*q + 0][srow] = w[q].x;
            Bs[scol + 4*q + 1][srow] = w[q].y;
            Bs[scol + 4*q + 2][srow] = w[q].z;
            Bs[scol + 4*q + 3][srow] = w[q].w;
        }
        __syncthreads();
        if (ch + 1 < nch) {                      // prefetch next chunk
            const int k0 = kbase + (ch + 1) * 32;
            const float4* Ap = (const float4*)&A[(m0 + srow) * 2048 + k0 + scol];
            const float4* Wp = (const float4*)&W[(n0 + srow) * 2048 + k0 + scol];
            #pragma unroll
            for (int q = 0; q < 4; ++q) a[q] = Ap[q];
            #pragma unroll
            for (int q = 0; q < 4; ++q) w[q] = Wp[q];
        }
        #pragma unroll
        for (int kk = 0; kk < 32; ++kk) {
            float4 af0 = *(const float4*)&As[kk][tm * 8];
            float4 af1 = *(const float4*)&As[kk][tm * 8 + 4];
            float4 bf0 = *(const float4*)&Bs[kk][tn * 8];
            float4 bf1 = *(const float4*)&Bs[kk][tn * 8 + 4];
            float av[8] = {af0.x,af0.y,af0.z,af0.w,af1.x,af1.y,af1.z,af1.w};
            float bv[8] = {bf0.x,bf0.y,bf0.z,bf0.w,bf1.x,bf1.y,bf1.z,bf1.w};
            #pragma unroll
            for (int r = 0; r < 8; ++r)
                #pragma unroll
                for (int c = 0; c < 8; ++c)
                    acc[r][c] += av[r] * bv[c];
        }
    }
    float* Pz = P + (size_t)blockIdx.z * 524288;   // 1024*512 per slab
    #pragma unroll
    for (int r = 0; r < 8; ++r) {
        float4 lo = make_float4(acc[r][0], acc[r][1], acc[r][2], acc[r][3]);
        float4 hi = make_float4(acc[r][4], acc[r][5], acc[r][6], acc[r][7]);
        float* dst = &Pz[(m0 + tm*8 + r) * 512 + n0 + tn*8];
        *(float4*)dst = lo;
        *(float4*)(dst + 4) = hi;
    }
}

// ==================================================================
// Kernel 2: reduce partials + bias -> com (written over slab 0).
// ==================================================================
__global__ __launch_bounds__(256) void reduce_kernel(float* __restrict__ P,
                                                     const float* __restrict__ bias,
                                                     int SK) {
    int i = blockIdx.x * 256 + threadIdx.x;        // 512K total
    float s = bias[i & 511];
    for (int z = 0; z < SK; ++z) s += P[z * 524288 + i];
    P[i] = s;
}

// ==================================================================
// Kernel 3: 12-qubit circuit, FOUR waves per batch element (256 thr),
// 16 complex amps per lane.
//   idx = (w1<<11) | (lane<<5) | (w0<<4) | e,  waveId = (w1<<1)|w0
//   V-wires (wave bits): wire0 -> vm=2, wire7 -> vm=1
//   L-wires (lane bits): wires1..6 -> lane bits 5..0
//   E-wires (reg bits):  wires8..11 -> e bits 3..0
// V-wire exchanges now run in TWO 8-amp half-passes through a 16 KB
// xbuf (total LDS 24 KB vs R5's 40 KB -> 2 blocks/CU was the
// occupancy cap at 24%).
// ==================================================================
struct CMat { float m00r,m00i,m01r,m01i,m10r,m10i,m11r,m11i; };

__device__ __forceinline__ CMat mk_rot(const float* __restrict__ qp, int l, int w) {
    const float* g = qp + (l * 12 + w) * 3;
    float phi = g[0], th = g[1], om = g[2];
    float st, ct, sa, ca, sb, cb;
    sincosf(0.5f * th, &st, &ct);
    sincosf(0.5f * (phi + om), &sa, &ca);
    sincosf(0.5f * (phi - om), &sb, &cb);
    CMat M;
    M.m00r =  ct * ca; M.m00i = -ct * sa;
    M.m01r = -st * cb; M.m01i = -st * sb;
    M.m10r =  st * cb; M.m10i = -st * sb;
    M.m11r =  ct * ca; M.m11i =  ct * sa;
    return M;
}

template<int W> struct WI {
    static constexpr int kind = (W == 0 || W == 7) ? 2 : ((W >= 1 && W <= 6) ? 1 : 0);
    static constexpr int eb   = (W >= 8) ? (11 - W) : 0;                 // E
    static constexpr int lm   = (W >= 1 && W <= 6) ? (1 << (6 - W)) : 0; // L
    static constexpr int vm   = (W == 0) ? 2 : ((W == 7) ? 1 : 0);       // V
};

// write own amps e = 8h..8h+7 (4 float4) into 16 KB xbuf
__device__ __forceinline__ void half_put(float* xbuf, int slot, int h,
                                         const float vr[16], const float vi[16]) {
    __syncthreads();                       // prior xbuf reads complete
    float4* p = (float4*)xbuf;
    #pragma unroll
    for (int j = 0; j < 4; ++j) {
        const int e = (h << 3) + 2*j;
        p[(j << 8) + slot] = make_float4(vr[e], vi[e], vr[e+1], vi[e+1]);
    }
    __syncthreads();
}

__device__ __forceinline__ void shfl_perm(float vr[16], float vi[16], int src) {
    #pragma unroll
    for (int e = 0; e < 16; ++e) {
        vr[e] = __shfl(vr[e], src, 64);
        vi[e] = __shfl(vi[e], src, 64);
    }
}

template<int EB>
__device__ __forceinline__ void rot_local(float vr[16], float vi[16], const CMat& M) {
    #pragma unroll
    for (int e = 0; e < 16; ++e) if (!(e & (1 << EB))) {
        const int e1 = e | (1 << EB);
        float x0r = vr[e],  x0i = vi[e];
        float x1r = vr[e1], x1i = vi[e1];
        vr[e]  = M.m00r*x0r - M.m00i*x0i + M.m01r*x1r - M.m01i*x1i;
        vi[e]  = M.m00r*x0i + M.m00i*x0r + M.m01r*x1i + M.m01i*x1r;
        vr[e1] = M.m10r*x0r - M.m10i*x0i + M.m11r*x1r - M.m11i*x1i;
        vi[e1] = M.m10r*x0i + M.m10i*x0r + M.m11r*x1i + M.m11i*x1r;
    }
}

template<int LM>
__device__ __forceinline__ void rot_lane(float vr[16], float vi[16], int lane, const CMat& M) {
    const bool hi = lane & LM;
    const float Ar = hi ? M.m11r : M.m00r, Ai = hi ? M.m11i : M.m00i;
    const float Br = hi ? M.m10r : M.m01r, Bi = hi ? M.m10i : M.m01i;
    #pragma unroll
    for (int e = 0; e < 16; ++e) {
        float pr = __shfl_xor(vr[e], LM, 64);
        float pi = __shfl_xor(vi[e], LM, 64);
        float orr = vr[e], oi = vi[e];
        vr[e] = Ar*orr - Ai*oi + Br*pr - Bi*pi;
        vi[e] = Ar*oi + Ai*orr + Br*pi + Bi*pr;
    }
}

template<int VM>
__device__ __forceinline__ void rot_wave(float vr[16], float vi[16], float* xbuf,
                                         int waveId, int lane, const CMat& M) {
    const int slot = (waveId << 6) + lane;
    const int ps = ((waveId ^ VM) << 6) + lane;
    const bool hi = waveId & VM;
    const float Ar = hi ? M.m11r : M.m00r, Ai = hi ? M.m11i : M.m00i;
    const float Br = hi ? M.m10r : M.m01r, Bi = hi ? M.m10i : M.m01i;
    #pragma unroll
    for (int h = 0; h < 2; ++h) {
        half_put(xbuf, slot, h, vr, vi);
        const float4* p = (const float4*)xbuf;
        #pragma unroll
        for (int j = 0; j < 4; ++j) {
            float4 q = p[(j << 8) + ps];
            const int e0 = (h << 3) + 2*j, e1 = e0 + 1;
            float r0 = vr[e0], i0 = vi[e0], r1 = vr[e1], i1 = vi[e1];
            vr[e0] = Ar*r0 - Ai*i0 + Br*q.x - Bi*q.y;
            vi[e0] = Ar*i0 + Ai*r0 + Br*q.y + Bi*q.x;
            vr[e1] = Ar*r1 - Ai*i1 + Br*q.z - Bi*q.w;
            vi[e1] = Ar*i1 + Ai*r1 + Br*q.w + Bi*q.z;
        }
    }
}

template<int W>
__device__ __forceinline__ void rot_wire(float vr[16], float vi[16], float* xbuf,
                                         int waveId, int lane, const CMat& M) {
    if constexpr (WI<W>::kind == 0)      rot_local<WI<W>::eb>(vr, vi, M);
    else if constexpr (WI<W>::kind == 1) rot_lane<WI<W>::lm>(vr, vi, lane, M);
    else                                 rot_wave<WI<W>::vm>(vr, vi, xbuf, waveId, lane, M);
}

template<int C, int T>
__device__ __forceinline__ void cnot(float vr[16], float vi[16], float* xbuf,
                                     int waveId, int lane) {
    constexpr int ck = WI<C>::kind, tk = WI<T>::kind;
    if constexpr (ck == 0 && tk == 0) {                       // E-E
        constexpr int cb = 1 << WI<C>::eb, tb = 1 << WI<T>::eb;
        #pragma unroll
        for (int e = 0; e < 16; ++e) if ((e & cb) && !(e & tb)) {
            const int e1 = e | tb;
            float t = vr[e]; vr[e] = vr[e1]; vr[e1] = t;
            t = vi[e]; vi[e] = vi[e1]; vi[e1] = t;
        }
    } else if constexpr (ck == 0 && tk == 1) {                // E-L
        constexpr int cb = 1 << WI<C>::eb, tm = WI<T>::lm;
        #pragma unroll
        for (int e = 0; e < 16; ++e) if (e & cb) {
            vr[e] = __shfl_xor(vr[e], tm, 64);
            vi[e] = __shfl_xor(vi[e], tm, 64);
        }
    } else if constexpr (ck == 0 && tk == 2) {                // E-V
        constexpr int cb = 1 << WI<C>::eb, vm = WI<T>::vm;
        const int slot = (waveId << 6) + lane;
        const int ps = ((waveId ^ vm) << 6) + lane;
        #pragma unroll
        for (int h = 0; h < 2; ++h) {
            half_put(xbuf, slot, h, vr, vi);
            const float4* p = (const float4*)xbuf;
            #pragma unroll
            for (int j = 0; j < 4; ++j) {
                const int e0 = (h << 3) + 2*j;
                if (((e0 & cb) != 0) || (((e0+1) & cb) != 0)) {
                    float4 q = p[(j << 8) + ps];
                    if ((e0 & cb) != 0)     { vr[e0]   = q.x; vi[e0]   = q.y; }
                    if (((e0+1) & cb) != 0) { vr[e0+1] = q.z; vi[e0+1] = q.w; }
                }
            }
        }
    } else if constexpr (ck == 1 && tk == 0) {                // L-E
        constexpr int cm = WI<C>::lm, tb = 1 << WI<T>::eb;
        const bool cc = lane & cm;
        #pragma unroll
        for (int e = 0; e < 16; ++e) if (!(e & tb)) {
            const int e1 = e | tb;
            float a = vr[e], bb = vr[e1];
            vr[e] = cc ? bb : a; vr[e1] = cc ? a : bb;
            a = vi[e]; bb = vi[e1];
            vi[e] = cc ? bb : a; vi[e1] = cc ? a : bb;
        }
    } else if constexpr (ck == 1 && tk == 1) {                // L-L
        constexpr int cm = WI<C>::lm, tm = WI<T>::lm;
        const int src = (lane & cm) ? (lane ^ tm) : lane;
        shfl_perm(vr, vi, src);
    } else if constexpr (ck == 1 && tk == 2) {                // L-V
        constexpr int cm = WI<C>::lm, vm = WI<T>::vm;
        const int slot = (waveId << 6) + lane;
        const int ps = ((waveId ^ vm) << 6) + lane;
        const bool take = lane & cm;
        #pragma unroll
        for (int h = 0; h < 2; ++h) {
            half_put(xbuf, slot, h, vr, vi);
            const float4* p = (const float4*)xbuf;
            #pragma unroll
            for (int j = 0; j < 4; ++j) {
                float4 q = p[(j << 8) + ps];
                const int e0 = (h << 3) + 2*j;
                vr[e0]   = take ? q.x : vr[e0];   vi[e0]   = take ? q.y : vi[e0];
                vr[e0+1] = take ? q.z : vr[e0+1]; vi[e0+1] = take ? q.w : vi[e0+1];
            }
        }
    } else if constexpr (ck == 2 && tk == 0) {                // V-E
        constexpr int vm = WI<C>::vm, tb = 1 << WI<T>::eb;
        if (waveId & vm) {
            #pragma unroll
            for (int e = 0; e < 16; ++e) if (!(e & tb)) {
                const int e1 = e | tb;
                float t = vr[e]; vr[e] = vr[e1]; vr[e1] = t;
                t = vi[e]; vi[e] = vi[e1]; vi[e1] = t;
            }
        }
    } else {                                                  // V-L
        constexpr int vm = WI<C>::vm, tm = WI<T>::lm;
        if (waveId & vm) {
            #pragma unroll
            for (int e = 0; e < 16; ++e) {
                vr[e] = __shfl_xor(vr[e], tm, 64);
                vi[e] = __shfl_xor(vi[e], tm, 64);
            }
        }
    }
}

template<int W>
__device__ __forceinline__ void h_wire(float vr[16], float vi[16], float* xbuf,
                                       int waveId, int lane) {
    if constexpr (WI<W>::kind == 0) {
        constexpr int tb = 1 << WI<W>::eb;
        #pragma unroll
        for (int e = 0; e < 16; ++e) if (!(e & tb)) {
            const int e1 = e | tb;
            float x0 = vr[e], x1 = vr[e1];
            vr[e] = (x0 + x1) * RS2f; vr[e1] = (x0 - x1) * RS2f;
            x0 = vi[e]; x1 = vi[e1];
            vi[e] = (x0 + x1) * RS2f; vi[e1] = (x0 - x1) * RS2f;
        }
    } else if constexpr (WI<W>::kind == 1) {
        constexpr int m = WI<W>::lm;
        const float sgn = (lane & m) ? -RS2f : RS2f;
        #pragma unroll
        for (int e = 0; e < 16; ++e) {
            float pr = __shfl_xor(vr[e], m, 64);
            float pi = __shfl_xor(vi[e], m, 64);
            vr[e] = pr * RS2f + vr[e] * sgn;
            vi[e] = pi * RS2f + vi[e] * sgn;
        }
    } else {
        constexpr int vm = WI<W>::vm;
        const int slot = (waveId << 6) + lane;
        const int ps = ((waveId ^ vm) << 6) + lane;
        const float sgn = (waveId & vm) ? -RS2f : RS2f;
        #pragma unroll
        for (int h = 0; h < 2; ++h) {
            half_put(xbuf, slot, h, vr, vi);
            const float4* p = (const float4*)xbuf;
            #pragma unroll
            for (int j = 0; j < 4; ++j) {
                float4 q = p[(j << 8) + ps];
                const int e0 = (h << 3) + 2*j;
                vr[e0]   = q.x * RS2f + vr[e0]   * sgn;
                vi[e0]   = q.y * RS2f + vi[e0]   * sgn;
                vr[e0+1] = q.z * RS2f + vr[e0+1] * sgn;
                vi[e0+1] = q.w * RS2f + vi[e0+1] * sgn;
            }
        }
    }
}

__global__ __launch_bounds__(256) void circuit_kernel(const float* __restrict__ com,  // (1024,512)
                                                      const float* __restrict__ xf,   // (1024,2048)
                                                      const float* __restrict__ qp,   // (2,12,3)
                                                      float* __restrict__ out) {
    __shared__ float xbuf[4096];         // 16 KB exchange buffer (half-pass)
    __shared__ float ang[2048];          // 8 KB: com row, later xf row
    const int tid = threadIdx.x;
    const int lane = tid & 63;
    const int waveId = tid >> 6;
    const int b = blockIdx.x;

    if (tid < 128) ((float4*)ang)[tid] = ((const float4*)(com + b * 512))[tid];
    __syncthreads();

    float vr[16], vi[16];
    #pragma unroll
    for (int e = 0; e < 16; ++e) { vr[e] = 0.0f; vi[e] = 0.0f; }

    // FRQI-1 closed form: amp nonzero where wires10,11 = 0 -> e in {0,4,8,12}
    const float K9 = 0.044194173824159216f;   // 2^-4.5
    #pragma unroll
    for (int m = 0; m < 4; ++m) {
        int j = (lane << 3) | ((waveId & 1) << 2) | m;   // wires1..9 value
        int rj = (int)(__brev((unsigned)j) >> 23);
        float s, c;
        sincosf(0.5f * ang[rj], &s, &c);
        vr[m << 2] = K9 * ((waveId & 2) ? s : c);
    }

    #pragma unroll 1
    for (int l = 0; l < 2; ++l) {
        { CMat M = mk_rot(qp, l, 0);  rot_wire<0 >(vr, vi, xbuf, waveId, lane, M); }
        { CMat M = mk_rot(qp, l, 1);  rot_wire<1 >(vr, vi, xbuf, waveId, lane, M); }
        { CMat M = mk_rot(qp, l, 2);  rot_wire<2 >(vr, vi, xbuf, waveId, lane, M); }
        { CMat M = mk_rot(qp, l, 3);  rot_wire<3 >(vr, vi, xbuf, waveId, lane, M); }
        { CMat M = mk_rot(qp, l, 4);  rot_wire<4 >(vr, vi, xbuf, waveId, lane, M); }
        { CMat M = mk_rot(qp, l, 5);  rot_wire<5 >(vr, vi, xbuf, waveId, lane, M); }
        { CMat M = mk_rot(qp, l, 6);  rot_wire<6 >(vr, vi, xbuf, waveId, lane, M); }
        { CMat M = mk_rot(qp, l, 7);  rot_wire<7 >(vr, vi, xbuf, waveId, lane, M); }
        { CMat M = mk_rot(qp, l, 8);  rot_wire<8 >(vr, vi, xbuf, waveId, lane, M); }
        { CMat M = mk_rot(qp, l, 9);  rot_wire<9 >(vr, vi, xbuf, waveId, lane, M); }
        { CMat M = mk_rot(qp, l, 10); rot_wire<10>(vr, vi, xbuf, waveId, lane, M); }
        { CMat M = mk_rot(qp, l, 11); rot_wire<11>(vr, vi, xbuf, waveId, lane, M); }
        if (l == 0) {                 // r = 1
            int j = lane;
            j ^= (j & 2)  ? 1  : 0;           // C(5,6)
            j ^= (j & 4)  ? 2  : 0;           // C(4,5)
            j ^= (j & 8)  ? 4  : 0;           // C(3,4)
            j ^= (j & 16) ? 8  : 0;           // C(2,3)
            j ^= (j & 32) ? 16 : 0;           // C(1,2)
            j ^= (waveId & 2) ? 32 : 0;       // C(0,1)
            shfl_perm(vr, vi, j);
            cnot<6,7>(vr,vi,xbuf,waveId,lane);   cnot<7,8>(vr,vi,xbuf,waveId,lane);
            cnot<8,9>(vr,vi,xbuf,waveId,lane);   cnot<9,10>(vr,vi,xbuf,waveId,lane);
            cnot<10,11>(vr,vi,xbuf,waveId,lane); cnot<11,0>(vr,vi,xbuf,waveId,lane);
        } else {                      // r = 2
            int j = lane;
            j ^= (j & 4)  ? 1  : 0;           // C(4,6)
            j ^= (j & 8)  ? 2  : 0;           // C(3,5)
            j ^= (j & 16) ? 4  : 0;           // C(2,4)
            j ^= (j & 32) ? 8  : 0;           // C(1,3)
            j ^= (waveId & 2) ? 16 : 0;       // C(0,2)
            shfl_perm(vr, vi, j);
            cnot<5,7>(vr,vi,xbuf,waveId,lane);   cnot<6,8>(vr,vi,xbuf,waveId,lane);
            cnot<7,9>(vr,vi,xbuf,waveId,lane);   cnot<8,10>(vr,vi,xbuf,waveId,lane);
            cnot<9,11>(vr,vi,xbuf,waveId,lane);  cnot<10,0>(vr,vi,xbuf,waveId,lane);
            cnot<11,1>(vr,vi,xbuf,waveId,lane);
        }
    }

    // FRQI-2 Hadamards on wires 1..11
    h_wire<1>(vr,vi,xbuf,waveId,lane);  h_wire<2>(vr,vi,xbuf,waveId,lane);
    h_wire<3>(vr,vi,xbuf,waveId,lane);  h_wire<4>(vr,vi,xbuf,waveId,lane);
    h_wire<5>(vr,vi,xbuf,waveId,lane);  h_wire<6>(vr,vi,xbuf,waveId,lane);
    h_wire<7>(vr,vi,xbuf,waveId,lane);  h_wire<8>(vr,vi,xbuf,waveId,lane);
    h_wire<9>(vr,vi,xbuf,waveId,lane);  h_wire<10>(vr,vi,xbuf,waveId,lane);
    h_wire<11>(vr,vi,xbuf,waveId,lane);

    // stage xf row
    {
        const float4* x4 = (const float4*)(xf + b * 2048);
        ((float4*)ang)[tid]       = x4[tid];
        ((float4*)ang)[tid + 256] = x4[tid + 256];
    }
    __syncthreads();

    // fused UC-RY(img) on wire0 (vm=2) + Z(0) expectation, half-pass
    {
        const int slot = (waveId << 6) + lane;
        const int ps = ((waveId ^ 2) << 6) + lane;
        const bool hi = waveId & 2;
        float acc = 0.0f;
        #pragma unroll
        for (int h = 0; h < 2; ++h) {
            half_put(xbuf, slot, h, vr, vi);
            const float4* p = (const float4*)xbuf;
            #pragma unroll
            for (int j = 0; j < 4; ++j) {
                float4 q = p[(j << 8) + ps];
                #pragma unroll
                for (int t = 0; t < 2; ++t) {
                    const int e = (h << 3) + 2*j + t;
                    const float prr = t ? q.z : q.x;
                    const float pii = t ? q.w : q.y;
                    int v = (lane << 5) | ((waveId & 1) << 4) | e;  // wires1..11
                    int rv = (int)(__brev((unsigned)v) >> 21);
                    float s, c;
                    sincosf(0.5f * ang[rv], &s, &c);
                    float nr = hi ? (s*prr + c*vr[e]) : (c*vr[e] - s*prr);
                    float ni = hi ? (s*pii + c*vi[e]) : (c*vi[e] - s*pii);
                    acc += nr*nr + ni*ni;
                }
            }
        }
        if (!hi) acc = -acc;
        #pragma unroll
        for (int off = 32; off > 0; off >>= 1) acc += __shfl_down(acc, off, 64);
        __syncthreads();
        if (lane == 0) xbuf[waveId] = acc;
        __syncthreads();
        if (tid == 0) out[b] = xbuf[0] + xbuf[1] + xbuf[2] + xbuf[3];
    }
}

extern "C" void kernel_launch(void* const* d_in, const int* in_sizes, int n_in,
                              void* d_out, int out_size, void* d_ws, size_t ws_size,
                              hipStream_t stream) {
    const float* x    = (const float*)d_in[0];   // (1024,2048)
    const float* W    = (const float*)d_in[1];   // (512,2048)
    const float* bias = (const float*)d_in[2];   // (512,)
    const float* qp   = (const float*)d_in[3];   // (2,12,3)
    float* out = (float*)d_out;                  // (1024,)
    float* P   = (float*)d_ws;                   // [SK][1024][512] partials

    const size_t slab = 1024 * 512 * sizeof(float);   // 2 MB
    int SK = 1;
    if      (ws_size >= 16 * slab) SK = 16;
    else if (ws_size >=  8 * slab) SK = 8;
    else if (ws_size >=  4 * slab) SK = 4;
    else if (ws_size >=  2 * slab) SK = 2;

    dim3 ggrid(8, 4, SK);                        // 128x128 tiles, split-K
    gemm_kernel<<<ggrid, 256, 0, stream>>>(x, W, P);
    reduce_kernel<<<2048, 256, 0, stream>>>(P, bias, SK);
    circuit_kernel<<<1024, 256, 0, stream>>>(P, x, qp, out);   // com = slab 0
}

// Round 7
// 168.223 us; speedup vs baseline: 1.1065x; 1.1065x over previous
//
#include <hip/hip_runtime.h>
#include <math.h>

#define RS2f 0.70710678118654752f

typedef __attribute__((ext_vector_type(8))) short bf16x8;
typedef __attribute__((ext_vector_type(4))) float f32x4;

__device__ __forceinline__ unsigned short f2bf(float f) {
    unsigned u = __float_as_uint(f);
    unsigned r = (u + 0x7fffu + ((u >> 16) & 1u)) >> 16;   // RNE
    return (unsigned short)r;
}
__device__ __forceinline__ float bf2f(unsigned short h) {
    return __uint_as_float(((unsigned)h) << 16);
}

// ==================================================================
// Kernel 1: split fp32 -> bf16 hi/lo pair, concat along K.
// src: (nrows, 2048) fp32.  dst: (nrows, 4096) bf16 = [hi | lo].
// x = hi + lo exactly to ~2^-17 rel; one K=4096 bf16 GEMM then equals
// the fp32 product including the lo*lo cross term's omission only at
// second order.
// ==================================================================
__global__ __launch_bounds__(256) void split_kernel(const float* __restrict__ src,
                                                    unsigned short* __restrict__ dst) {
    int idx = blockIdx.x * 256 + threadIdx.x;      // nrows*512 total
    int m = idx >> 9;
    int c4 = (idx & 511) << 2;
    const float4 v = *(const float4*)&src[m * 2048 + c4];
    ushort4 hi, lo;
    hi.x = f2bf(v.x); lo.x = f2bf(v.x - bf2f(hi.x));
    hi.y = f2bf(v.y); lo.y = f2bf(v.y - bf2f(hi.y));
    hi.z = f2bf(v.z); lo.z = f2bf(v.z - bf2f(hi.z));
    hi.w = f2bf(v.w); lo.w = f2bf(v.w - bf2f(hi.w));
    *(ushort4*)&dst[m * 4096 + c4] = hi;
    *(ushort4*)&dst[m * 4096 + 2048 + c4] = lo;
}

// ==================================================================
// Kernel 2: MFMA GEMM. com[m][n] = sum_k xc[m][k] wc[n][k] + bias[n].
// M=1024,N=512,K=4096 bf16 (split pairs), fp32 accumulate.
// Block tile 64(M)x32(N), BK=64, 4 waves (wave w: rows 16w..16w+15).
// 16x16x32 MFMA; A/B frags are 16B ds_read_b128 from padded K-major
// tiles (stride 72 bf16 -> 2-way banks = free). Grid 16x16 = 256.
// ==================================================================
__global__ __launch_bounds__(256) void gemm_mfma(const unsigned short* __restrict__ A,  // 1024x4096
                                                 const unsigned short* __restrict__ B,  // 512x4096
                                                 const float* __restrict__ bias,
                                                 float* __restrict__ C) {               // 1024x512
    __shared__ short As[64 * 72];
    __shared__ short Bs[32 * 72];
    const int tid = threadIdx.x;
    const int lane = tid & 63;
    const int wv = tid >> 6;
    const int m0 = blockIdx.x * 64;
    const int n0 = blockIdx.y * 32;
    const int quad = lane >> 4, mrow = lane & 15;
    const int srow = tid >> 3;            // 0..31
    const int sk8 = (tid & 7) * 8;        // 0..56
    f32x4 acc0 = {0.f, 0.f, 0.f, 0.f};
    f32x4 acc1 = {0.f, 0.f, 0.f, 0.f};
    for (int k0 = 0; k0 < 4096; k0 += 64) {
        float4 a0 = *(const float4*)&A[(size_t)(m0 + srow) * 4096 + k0 + sk8];
        float4 a1 = *(const float4*)&A[(size_t)(m0 + srow + 32) * 4096 + k0 + sk8];
        float4 b0 = *(const float4*)&B[(size_t)(n0 + srow) * 4096 + k0 + sk8];
        __syncthreads();
        *(float4*)&As[srow * 72 + sk8] = a0;
        *(float4*)&As[(srow + 32) * 72 + sk8] = a1;
        *(float4*)&Bs[srow * 72 + sk8] = b0;
        __syncthreads();
        #pragma unroll
        for (int ks = 0; ks < 2; ++ks) {
            bf16x8 af  = *(const bf16x8*)&As[(wv * 16 + mrow) * 72 + ks * 32 + quad * 8];
            bf16x8 bf0 = *(const bf16x8*)&Bs[mrow * 72 + ks * 32 + quad * 8];
            bf16x8 bf1 = *(const bf16x8*)&Bs[(16 + mrow) * 72 + ks * 32 + quad * 8];
            acc0 = __builtin_amdgcn_mfma_f32_16x16x32_bf16(af, bf0, acc0, 0, 0, 0);
            acc1 = __builtin_amdgcn_mfma_f32_16x16x32_bf16(af, bf1, acc1, 0, 0, 0);
        }
    }
    // C/D layout: col = lane&15, row = quad*4 + r
    const float bv0 = bias[n0 + mrow];
    const float bv1 = bias[n0 + 16 + mrow];
    #pragma unroll
    for (int r = 0; r < 4; ++r) {
        int m = m0 + wv * 16 + quad * 4 + r;
        C[m * 512 + n0 + mrow]      = acc0[r] + bv0;
        C[m * 512 + n0 + 16 + mrow] = acc1[r] + bv1;
    }
}

// ==================================================================
// Fallback fp32 GEMM (only if ws too small for the split buffers)
// ==================================================================
__global__ __launch_bounds__(256) void gemm_f32(const float* __restrict__ A,
                                                const float* __restrict__ W,
                                                float* __restrict__ P) {
    __shared__ float Asf[32][128];
    __shared__ float Bsf[32][128];
    const int tid = threadIdx.x;
    const int m0 = blockIdx.x * 128;
    const int n0 = blockIdx.y * 128;
    const int kchunk = 2048 / gridDim.z;
    const int kbase = blockIdx.z * kchunk;
    const int tm = tid >> 4, tn = tid & 15;
    const int srow = tid >> 1;
    const int scol = (tid & 1) * 16;
    float acc[8][8] = {};
    for (int k0 = kbase; k0 < kbase + kchunk; k0 += 32) {
        float4 a[4], w[4];
        const float4* Ap = (const float4*)&A[(m0 + srow) * 2048 + k0 + scol];
        const float4* Wp = (const float4*)&W[(n0 + srow) * 2048 + k0 + scol];
        #pragma unroll
        for (int q = 0; q < 4; ++q) { a[q] = Ap[q]; w[q] = Wp[q]; }
        __syncthreads();
        #pragma unroll
        for (int q = 0; q < 4; ++q) {
            Asf[scol + 4*q + 0][srow] = a[q].x; Asf[scol + 4*q + 1][srow] = a[q].y;
            Asf[scol + 4*q + 2][srow] = a[q].z; Asf[scol + 4*q + 3][srow] = a[q].w;
            Bsf[scol + 4*q + 0][srow] = w[q].x; Bsf[scol + 4*q + 1][srow] = w[q].y;
            Bsf[scol + 4*q + 2][srow] = w[q].z; Bsf[scol + 4*q + 3][srow] = w[q].w;
        }
        __syncthreads();
        #pragma unroll
        for (int kk = 0; kk < 32; ++kk) {
            float4 af0 = *(const float4*)&Asf[kk][tm * 8];
            float4 af1 = *(const float4*)&Asf[kk][tm * 8 + 4];
            float4 bf0 = *(const float4*)&Bsf[kk][tn * 8];
            float4 bf1 = *(const float4*)&Bsf[kk][tn * 8 + 4];
            float av[8] = {af0.x,af0.y,af0.z,af0.w,af1.x,af1.y,af1.z,af1.w};
            float bv[8] = {bf0.x,bf0.y,bf0.z,bf0.w,bf1.x,bf1.y,bf1.z,bf1.w};
            #pragma unroll
            for (int r = 0; r < 8; ++r)
                #pragma unroll
                for (int c = 0; c < 8; ++c)
                    acc[r][c] += av[r] * bv[c];
        }
    }
    float* Pz = P + (size_t)blockIdx.z * 524288;
    #pragma unroll
    for (int r = 0; r < 8; ++r) {
        float4 lo = make_float4(acc[r][0], acc[r][1], acc[r][2], acc[r][3]);
        float4 hi = make_float4(acc[r][4], acc[r][5], acc[r][6], acc[r][7]);
        float* dst = &Pz[(m0 + tm*8 + r) * 512 + n0 + tn*8];
        *(float4*)dst = lo;
        *(float4*)(dst + 4) = hi;
    }
}

__global__ __launch_bounds__(256) void reduce_kernel(float* __restrict__ P,
                                                     const float* __restrict__ bias,
                                                     int SK) {
    int i = blockIdx.x * 256 + threadIdx.x;
    float s = bias[i & 511];
    for (int z = 0; z < SK; ++z) s += P[z * 524288 + i];
    P[i] = s;
}

// ==================================================================
// Kernel 3: 12-qubit circuit, R5 structure (full 32 KB exchanges --
// R6 showed halving LDS does NOT raise occupancy but doubling
// barriers costs ~10%). New: 24 Rot matrices computed ONCE per block
// by 24 threads into LDS instead of per-wave-per-lane sincosf.
//   idx = (w1<<11) | (lane<<5) | (w0<<4) | e,  waveId = (w1<<1)|w0
//   V-wires: wire0 -> vm=2, wire7 -> vm=1
//   L-wires: wires1..6 -> lane bits 5..0
//   E-wires: wires8..11 -> e bits 3..0
// ==================================================================
struct CMat { float m00r,m00i,m01r,m01i,m10r,m10i,m11r,m11i; };

__device__ __forceinline__ CMat mk_rot(const float* __restrict__ qp, int l, int w) {
    const float* g = qp + (l * 12 + w) * 3;
    float phi = g[0], th = g[1], om = g[2];
    float st, ct, sa, ca, sb, cb;
    sincosf(0.5f * th, &st, &ct);
    sincosf(0.5f * (phi + om), &sa, &ca);
    sincosf(0.5f * (phi - om), &sb, &cb);
    CMat M;
    M.m00r =  ct * ca; M.m00i = -ct * sa;
    M.m01r = -st * cb; M.m01i = -st * sb;
    M.m10r =  st * cb; M.m10i = -st * sb;
    M.m11r =  ct * ca; M.m11i =  ct * sa;
    return M;
}

__device__ __forceinline__ CMat ld_cmat(const float4* cmt, int idx) {
    float4 a = cmt[idx * 2], b = cmt[idx * 2 + 1];
    CMat M = {a.x, a.y, a.z, a.w, b.x, b.y, b.z, b.w};
    return M;
}

template<int W> struct WI {
    static constexpr int kind = (W == 0 || W == 7) ? 2 : ((W >= 1 && W <= 6) ? 1 : 0);
    static constexpr int eb   = (W >= 8) ? (11 - W) : 0;
    static constexpr int lm   = (W >= 1 && W <= 6) ? (1 << (6 - W)) : 0;
    static constexpr int vm   = (W == 0) ? 2 : ((W == 7) ? 1 : 0);
};

__device__ __forceinline__ void exch_put(float* xbuf, int slot,
                                         const float vr[16], const float vi[16]) {
    __syncthreads();
    float4* p = (float4*)xbuf;
    #pragma unroll
    for (int j = 0; j < 8; ++j)
        p[(j << 8) + slot] = make_float4(vr[2*j], vi[2*j], vr[2*j+1], vi[2*j+1]);
    __syncthreads();
}

__device__ __forceinline__ void shfl_perm(float vr[16], float vi[16], int src) {
    #pragma unroll
    for (int e = 0; e < 16; ++e) {
        vr[e] = __shfl(vr[e], src, 64);
        vi[e] = __shfl(vi[e], src, 64);
    }
}

template<int EB>
__device__ __forceinline__ void rot_local(float vr[16], float vi[16], const CMat& M) {
    #pragma unroll
    for (int e = 0; e < 16; ++e) if (!(e & (1 << EB))) {
        const int e1 = e | (1 << EB);
        float x0r = vr[e],  x0i = vi[e];
        float x1r = vr[e1], x1i = vi[e1];
        vr[e]  = M.m00r*x0r - M.m00i*x0i + M.m01r*x1r - M.m01i*x1i;
        vi[e]  = M.m00r*x0i + M.m00i*x0r + M.m01r*x1i + M.m01i*x1r;
        vr[e1] = M.m10r*x0r - M.m10i*x0i + M.m11r*x1r - M.m11i*x1i;
        vi[e1] = M.m10r*x0i + M.m10i*x0r + M.m11r*x1i + M.m11i*x1r;
    }
}

template<int LM>
__device__ __forceinline__ void rot_lane(float vr[16], float vi[16], int lane, const CMat& M) {
    const bool hi = lane & LM;
    const float Ar = hi ? M.m11r : M.m00r, Ai = hi ? M.m11i : M.m00i;
    const float Br = hi ? M.m10r : M.m01r, Bi = hi ? M.m10i : M.m01i;
    #pragma unroll
    for (int e = 0; e < 16; ++e) {
        float pr = __shfl_xor(vr[e], LM, 64);
        float pi = __shfl_xor(vi[e], LM, 64);
        float orr = vr[e], oi = vi[e];
        vr[e] = Ar*orr - Ai*oi + Br*pr - Bi*pi;
        vi[e] = Ar*oi + Ai*orr + Br*pi + Bi*pr;
    }
}

template<int VM>
__device__ __forceinline__ void rot_wave(float vr[16], float vi[16], float* xbuf,
                                         int waveId, int lane, const CMat& M) {
    exch_put(xbuf, (waveId << 6) + lane, vr, vi);
    const float4* p = (const float4*)xbuf;
    const int ps = ((waveId ^ VM) << 6) + lane;
    const bool hi = waveId & VM;
    const float Ar = hi ? M.m11r : M.m00r, Ai = hi ? M.m11i : M.m00i;
    const float Br = hi ? M.m10r : M.m01r, Bi = hi ? M.m10i : M.m01i;
    #pragma unroll
    for (int j = 0; j < 8; ++j) {
        float4 q = p[(j << 8) + ps];
        const int e0 = 2*j, e1 = 2*j + 1;
        float r0 = vr[e0], i0 = vi[e0], r1 = vr[e1], i1 = vi[e1];
        vr[e0] = Ar*r0 - Ai*i0 + Br*q.x - Bi*q.y;
        vi[e0] = Ar*i0 + Ai*r0 + Br*q.y + Bi*q.x;
        vr[e1] = Ar*r1 - Ai*i1 + Br*q.z - Bi*q.w;
        vi[e1] = Ar*i1 + Ai*r1 + Br*q.w + Bi*q.z;
    }
}

template<int W>
__device__ __forceinline__ void rot_wire(float vr[16], float vi[16], float* xbuf,
                                         int waveId, int lane, const CMat& M) {
    if constexpr (WI<W>::kind == 0)      rot_local<WI<W>::eb>(vr, vi, M);
    else if constexpr (WI<W>::kind == 1) rot_lane<WI<W>::lm>(vr, vi, lane, M);
    else                                 rot_wave<WI<W>::vm>(vr, vi, xbuf, waveId, lane, M);
}

template<int C, int T>
__device__ __forceinline__ void cnot(float vr[16], float vi[16], float* xbuf,
                                     int waveId, int lane) {
    constexpr int ck = WI<C>::kind, tk = WI<T>::kind;
    if constexpr (ck == 0 && tk == 0) {
        constexpr int cb = 1 << WI<C>::eb, tb = 1 << WI<T>::eb;
        #pragma unroll
        for (int e = 0; e < 16; ++e) if ((e & cb) && !(e & tb)) {
            const int e1 = e | tb;
            float t = vr[e]; vr[e] = vr[e1]; vr[e1] = t;
            t = vi[e]; vi[e] = vi[e1]; vi[e1] = t;
        }
    } else if constexpr (ck == 0 && tk == 1) {
        constexpr int cb = 1 << WI<C>::eb, tm = WI<T>::lm;
        #pragma unroll
        for (int e = 0; e < 16; ++e) if (e & cb) {
            vr[e] = __shfl_xor(vr[e], tm, 64);
            vi[e] = __shfl_xor(vi[e], tm, 64);
        }
    } else if constexpr (ck == 0 && tk == 2) {
        constexpr int cb = 1 << WI<C>::eb, vm = WI<T>::vm;
        exch_put(xbuf, (waveId << 6) + lane, vr, vi);
        const float4* p = (const float4*)xbuf;
        const int ps = ((waveId ^ vm) << 6) + lane;
        #pragma unroll
        for (int j = 0; j < 8; ++j) {
            if ((((2*j) & cb) != 0) || (((2*j+1) & cb) != 0)) {
                float4 q = p[(j << 8) + ps];
                if (((2*j) & cb) != 0)   { vr[2*j]   = q.x; vi[2*j]   = q.y; }
                if (((2*j+1) & cb) != 0) { vr[2*j+1] = q.z; vi[2*j+1] = q.w; }
            }
        }
    } else if constexpr (ck == 1 && tk == 0) {
        constexpr int cm = WI<C>::lm, tb = 1 << WI<T>::eb;
        const bool cc = lane & cm;
        #pragma unroll
        for (int e = 0; e < 16; ++e) if (!(e & tb)) {
            const int e1 = e | tb;
            float a = vr[e], bb = vr[e1];
            vr[e] = cc ? bb : a; vr[e1] = cc ? a : bb;
            a = vi[e]; bb = vi[e1];
            vi[e] = cc ? bb : a; vi[e1] = cc ? a : bb;
        }
    } else if constexpr (ck == 1 && tk == 1) {
        constexpr int cm = WI<C>::lm, tm = WI<T>::lm;
        const int src = (lane & cm) ? (lane ^ tm) : lane;
        shfl_perm(vr, vi, src);
    } else if constexpr (ck == 1 && tk == 2) {
        constexpr int cm = WI<C>::lm, vm = WI<T>::vm;
        exch_put(xbuf, (waveId << 6) + lane, vr, vi);
        const float4* p = (const float4*)xbuf;
        const int ps = ((waveId ^ vm) << 6) + lane;
        const bool take = lane & cm;
        #pragma unroll
        for (int j = 0; j < 8; ++j) {
            float4 q = p[(j << 8) + ps];
            vr[2*j]   = take ? q.x : vr[2*j];   vi[2*j]   = take ? q.y : vi[2*j];
            vr[2*j+1] = take ? q.z : vr[2*j+1]; vi[2*j+1] = take ? q.w : vi[2*j+1];
        }
    } else if constexpr (ck == 2 && tk == 0) {
        constexpr int vm = WI<C>::vm, tb = 1 << WI<T>::eb;
        if (waveId & vm) {
            #pragma unroll
            for (int e = 0; e < 16; ++e) if (!(e & tb)) {
                const int e1 = e | tb;
                float t = vr[e]; vr[e] = vr[e1]; vr[e1] = t;
                t = vi[e]; vi[e] = vi[e1]; vi[e1] = t;
            }
        }
    } else {
        constexpr int vm = WI<C>::vm, tm = WI<T>::lm;
        if (waveId & vm) {
            #pragma unroll
            for (int e = 0; e < 16; ++e) {
                vr[e] = __shfl_xor(vr[e], tm, 64);
                vi[e] = __shfl_xor(vi[e], tm, 64);
            }
        }
    }
}

template<int W>
__device__ __forceinline__ void h_wire(float vr[16], float vi[16], float* xbuf,
                                       int waveId, int lane) {
    if constexpr (WI<W>::kind == 0) {
        constexpr int tb = 1 << WI<W>::eb;
        #pragma unroll
        for (int e = 0; e < 16; ++e) if (!(e & tb)) {
            const int e1 = e | tb;
            float x0 = vr[e], x1 = vr[e1];
            vr[e] = (x0 + x1) * RS2f; vr[e1] = (x0 - x1) * RS2f;
            x0 = vi[e]; x1 = vi[e1];
            vi[e] = (x0 + x1) * RS2f; vi[e1] = (x0 - x1) * RS2f;
        }
    } else if constexpr (WI<W>::kind == 1) {
        constexpr int m = WI<W>::lm;
        const float sgn = (lane & m) ? -RS2f : RS2f;
        #pragma unroll
        for (int e = 0; e < 16; ++e) {
            float pr = __shfl_xor(vr[e], m, 64);
            float pi = __shfl_xor(vi[e], m, 64);
            vr[e] = pr * RS2f + vr[e] * sgn;
            vi[e] = pi * RS2f + vi[e] * sgn;
        }
    } else {
        constexpr int vm = WI<W>::vm;
        exch_put(xbuf, (waveId << 6) + lane, vr, vi);
        const float4* p = (const float4*)xbuf;
        const int ps = ((waveId ^ vm) << 6) + lane;
        const float sgn = (waveId & vm) ? -RS2f : RS2f;
        #pragma unroll
        for (int j = 0; j < 8; ++j) {
            float4 q = p[(j << 8) + ps];
            vr[2*j]   = q.x * RS2f + vr[2*j]   * sgn;
            vi[2*j]   = q.y * RS2f + vi[2*j]   * sgn;
            vr[2*j+1] = q.z * RS2f + vr[2*j+1] * sgn;
            vi[2*j+1] = q.w * RS2f + vi[2*j+1] * sgn;
        }
    }
}

__global__ __launch_bounds__(256) void circuit_kernel(const float* __restrict__ com,
                                                      const float* __restrict__ xf,
                                                      const float* __restrict__ qp,
                                                      float* __restrict__ out) {
    __shared__ float xbuf[8192];         // 32 KB exchange buffer
    __shared__ float ang[2048];          // 8 KB: com row, later xf row
    __shared__ float4 cmt[48];           // 24 Rot matrices, 2 float4 each
    const int tid = threadIdx.x;
    const int lane = tid & 63;
    const int waveId = tid >> 6;
    const int b = blockIdx.x;

    if (tid < 128) ((float4*)ang)[tid] = ((const float4*)(com + b * 512))[tid];
    if (tid >= 128 && tid < 152) {       // 24 threads build the gate matrices
        int g = tid - 128;
        CMat M = mk_rot(qp, g / 12, g % 12);
        cmt[g * 2]     = make_float4(M.m00r, M.m00i, M.m01r, M.m01i);
        cmt[g * 2 + 1] = make_float4(M.m10r, M.m10i, M.m11r, M.m11i);
    }
    __syncthreads();

    float vr[16], vi[16];
    #pragma unroll
    for (int e = 0; e < 16; ++e) { vr[e] = 0.0f; vi[e] = 0.0f; }

    // FRQI-1 closed form: amp nonzero where wires10,11 = 0 -> e in {0,4,8,12}
    const float K9 = 0.044194173824159216f;   // 2^-4.5
    #pragma unroll
    for (int m = 0; m < 4; ++m) {
        int j = (lane << 3) | ((waveId & 1) << 2) | m;
        int rj = (int)(__brev((unsigned)j) >> 23);
        float s, c;
        sincosf(0.5f * ang[rj], &s, &c);
        vr[m << 2] = K9 * ((waveId & 2) ? s : c);
    }

    #pragma unroll 1
    for (int l = 0; l < 2; ++l) {
        const int lb = l * 12;
        { CMat M = ld_cmat(cmt, lb + 0);  rot_wire<0 >(vr, vi, xbuf, waveId, lane, M); }
        { CMat M = ld_cmat(cmt, lb + 1);  rot_wire<1 >(vr, vi, xbuf, waveId, lane, M); }
        { CMat M = ld_cmat(cmt, lb + 2);  rot_wire<2 >(vr, vi, xbuf, waveId, lane, M); }
        { CMat M = ld_cmat(cmt, lb + 3);  rot_wire<3 >(vr, vi, xbuf, waveId, lane, M); }
        { CMat M = ld_cmat(cmt, lb + 4);  rot_wire<4 >(vr, vi, xbuf, waveId, lane, M); }
        { CMat M = ld_cmat(cmt, lb + 5);  rot_wire<5 >(vr, vi, xbuf, waveId, lane, M); }
        { CMat M = ld_cmat(cmt, lb + 6);  rot_wire<6 >(vr, vi, xbuf, waveId, lane, M); }
        { CMat M = ld_cmat(cmt, lb + 7);  rot_wire<7 >(vr, vi, xbuf, waveId, lane, M); }
        { CMat M = ld_cmat(cmt, lb + 8);  rot_wire<8 >(vr, vi, xbuf, waveId, lane, M); }
        { CMat M = ld_cmat(cmt, lb + 9);  rot_wire<9 >(vr, vi, xbuf, waveId, lane, M); }
        { CMat M = ld_cmat(cmt, lb + 10); rot_wire<10>(vr, vi, xbuf, waveId, lane, M); }
        { CMat M = ld_cmat(cmt, lb + 11); rot_wire<11>(vr, vi, xbuf, waveId, lane, M); }
        if (l == 0) {                 // r = 1
            int j = lane;
            j ^= (j & 2)  ? 1  : 0;           // C(5,6)
            j ^= (j & 4)  ? 2  : 0;           // C(4,5)
            j ^= (j & 8)  ? 4  : 0;           // C(3,4)
            j ^= (j & 16) ? 8  : 0;           // C(2,3)
            j ^= (j & 32) ? 16 : 0;           // C(1,2)
            j ^= (waveId & 2) ? 32 : 0;       // C(0,1)
            shfl_perm(vr, vi, j);
            cnot<6,7>(vr,vi,xbuf,waveId,lane);   cnot<7,8>(vr,vi,xbuf,waveId,lane);
            cnot<8,9>(vr,vi,xbuf,waveId,lane);   cnot<9,10>(vr,vi,xbuf,waveId,lane);
            cnot<10,11>(vr,vi,xbuf,waveId,lane); cnot<11,0>(vr,vi,xbuf,waveId,lane);
        } else {                      // r = 2
            int j = lane;
            j ^= (j & 4)  ? 1  : 0;           // C(4,6)
            j ^= (j & 8)  ? 2  : 0;           // C(3,5)
            j ^= (j & 16) ? 4  : 0;           // C(2,4)
            j ^= (j & 32) ? 8  : 0;           // C(1,3)
            j ^= (waveId & 2) ? 16 : 0;       // C(0,2)
            shfl_perm(vr, vi, j);
            cnot<5,7>(vr,vi,xbuf,waveId,lane);   cnot<6,8>(vr,vi,xbuf,waveId,lane);
            cnot<7,9>(vr,vi,xbuf,waveId,lane);   cnot<8,10>(vr,vi,xbuf,waveId,lane);
            cnot<9,11>(vr,vi,xbuf,waveId,lane);  cnot<10,0>(vr,vi,xbuf,waveId,lane);
            cnot<11,1>(vr,vi,xbuf,waveId,lane);
        }
    }

    // FRQI-2 Hadamards on wires 1..11
    h_wire<1>(vr,vi,xbuf,waveId,lane);  h_wire<2>(vr,vi,xbuf,waveId,lane);
    h_wire<3>(vr,vi,xbuf,waveId,lane);  h_wire<4>(vr,vi,xbuf,waveId,lane);
    h_wire<5>(vr,vi,xbuf,waveId,lane);  h_wire<6>(vr,vi,xbuf,waveId,lane);
    h_wire<7>(vr,vi,xbuf,waveId,lane);  h_wire<8>(vr,vi,xbuf,waveId,lane);
    h_wire<9>(vr,vi,xbuf,waveId,lane);  h_wire<10>(vr,vi,xbuf,waveId,lane);
    h_wire<11>(vr,vi,xbuf,waveId,lane);

    // stage xf row
    {
        const float4* x4 = (const float4*)(xf + b * 2048);
        ((float4*)ang)[tid]       = x4[tid];
        ((float4*)ang)[tid + 256] = x4[tid + 256];
    }
    __syncthreads();

    // fused UC-RY(img) on wire0 (vm=2) + Z(0) expectation
    exch_put(xbuf, (waveId << 6) + lane, vr, vi);
    {
        const float4* p = (const float4*)xbuf;
        const int ps = ((waveId ^ 2) << 6) + lane;
        const bool hi = waveId & 2;
        float acc = 0.0f;
        #pragma unroll
        for (int j = 0; j < 8; ++j) {
            float4 q = p[(j << 8) + ps];
            #pragma unroll
            for (int h = 0; h < 2; ++h) {
                const int e = 2*j + h;
                const float prr = h ? q.z : q.x;
                const float pii = h ? q.w : q.y;
                int v = (lane << 5) | ((waveId & 1) << 4) | e;
                int rv = (int)(__brev((unsigned)v) >> 21);
                float s, c;
                sincosf(0.5f * ang[rv], &s, &c);
                float nr = hi ? (s*prr + c*vr[e]) : (c*vr[e] - s*prr);
                float ni = hi ? (s*pii + c*vi[e]) : (c*vi[e] - s*pii);
                acc += nr*nr + ni*ni;
            }
        }
        if (!hi) acc = -acc;
        #pragma unroll
        for (int off = 32; off > 0; off >>= 1) acc += __shfl_down(acc, off, 64);
        __syncthreads();
        if (lane == 0) xbuf[waveId] = acc;
        __syncthreads();
        if (tid == 0) out[b] = xbuf[0] + xbuf[1] + xbuf[2] + xbuf[3];
    }
}

extern "C" void kernel_launch(void* const* d_in, const int* in_sizes, int n_in,
                              void* d_out, int out_size, void* d_ws, size_t ws_size,
                              hipStream_t stream) {
    const float* x    = (const float*)d_in[0];   // (1024,2048)
    const float* W    = (const float*)d_in[1];   // (512,2048)
    const float* bias = (const float*)d_in[2];   // (512,)
    const float* qp   = (const float*)d_in[3];   // (2,12,3)
    float* out = (float*)d_out;                  // (1024,)

    // ws layout (MFMA path): xc 8 MB | wc 4 MB | com 2 MB
    const size_t XC = 1024ull * 4096 * 2;        // 8 MB
    const size_t WC = 512ull * 4096 * 2;         // 4 MB
    const size_t CM = 1024ull * 512 * 4;         // 2 MB
    if (ws_size >= XC + WC + CM) {
        unsigned short* xc = (unsigned short*)d_ws;
        unsigned short* wc = (unsigned short*)((char*)d_ws + XC);
        float* com = (float*)((char*)d_ws + XC + WC);
        split_kernel<<<2048, 256, 0, stream>>>(x, xc);    // 1024 rows
        split_kernel<<<1024, 256, 0, stream>>>(W, wc);    // 512 rows
        dim3 g(16, 16);
        gemm_mfma<<<g, 256, 0, stream>>>(xc, wc, bias, com);
        circuit_kernel<<<1024, 256, 0, stream>>>(com, x, qp, out);
    } else {
        // fallback: fp32 split-K partials + reduce (R5 path)
        float* P = (float*)d_ws;
        const size_t slab = 1024 * 512 * sizeof(float);
        int SK = 1;
        if      (ws_size >= 16 * slab) SK = 16;
        else if (ws_size >=  8 * slab) SK = 8;
        else if (ws_size >=  4 * slab) SK = 4;
        else if (ws_size >=  2 * slab) SK = 2;
        dim3 ggrid(8, 4, SK);
        gemm_f32<<<ggrid, 256, 0, stream>>>(x, W, P);
        reduce_kernel<<<2048, 256, 0, stream>>>(P, bias, SK);
        circuit_kernel<<<1024, 256, 0, stream>>>(P, x, qp, out);
    }
}

// Round 8
// 156.438 us; speedup vs baseline: 1.1898x; 1.0753x over previous
//
#include <hip/hip_runtime.h>
#include <math.h>

#define RS2f 0.70710678118654752f

typedef __attribute__((ext_vector_type(8))) short bf16x8;
typedef __attribute__((ext_vector_type(4))) float f32x4;

__device__ __forceinline__ unsigned short f2bf(float f) {
    unsigned u = __float_as_uint(f);
    unsigned r = (u + 0x7fffu + ((u >> 16) & 1u)) >> 16;   // RNE
    return (unsigned short)r;
}
__device__ __forceinline__ float bf2f(unsigned short h) {
    return __uint_as_float(((unsigned)h) << 16);
}

// ==================================================================
// split fp32 -> bf16 hi/lo pair, concat along K (row stride 2*ncols).
// ==================================================================
__global__ __launch_bounds__(256) void split_kernel(const float* __restrict__ src,
                                                    unsigned short* __restrict__ dst) {
    int idx = blockIdx.x * 256 + threadIdx.x;      // nrows*512 total
    int m = idx >> 9;
    int c4 = (idx & 511) << 2;
    const float4 v = *(const float4*)&src[m * 2048 + c4];
    ushort4 hi, lo;
    hi.x = f2bf(v.x); lo.x = f2bf(v.x - bf2f(hi.x));
    hi.y = f2bf(v.y); lo.y = f2bf(v.y - bf2f(hi.y));
    hi.z = f2bf(v.z); lo.z = f2bf(v.z - bf2f(hi.z));
    hi.w = f2bf(v.w); lo.w = f2bf(v.w - bf2f(hi.w));
    *(ushort4*)&dst[m * 4096 + c4] = hi;
    *(ushort4*)&dst[m * 4096 + 2048 + c4] = lo;
}

// hi-only convert (for the 14 MB ws layout): dst stride 2048
__global__ __launch_bounds__(256) void conv_hi(const float* __restrict__ src,
                                               unsigned short* __restrict__ dst) {
    int idx = blockIdx.x * 256 + threadIdx.x;      // nrows*512 total
    int m = idx >> 9;
    int c4 = (idx & 511) << 2;
    const float4 v = *(const float4*)&src[m * 2048 + c4];
    ushort4 h;
    h.x = f2bf(v.x); h.y = f2bf(v.y); h.z = f2bf(v.z); h.w = f2bf(v.w);
    *(ushort4*)&dst[m * 2048 + c4] = h;
}

// ==================================================================
// MFMA GEMM partials, split-K=2 over the bf16 halves.
// P[z][m][n] = sum_{k<2048} A[m][z*2048+k] * B[n][bcol_z + k]
// Tile 64(M)x32(N), BK=64, 4 waves, 16x16x32 MFMA, register prefetch.
// Grid (16,16,2) = 512 blocks = 2/CU (R7's 256 = 1/CU was the stall).
// ==================================================================
__global__ __launch_bounds__(256) void gemm_mfma(const unsigned short* __restrict__ A,  // 1024x4096
                                                 const unsigned short* __restrict__ B,  // 512xBstride
                                                 int Bstride, int Bcol1,
                                                 float* __restrict__ P) {
    __shared__ short As[64 * 72];
    __shared__ short Bs[32 * 72];
    const int tid = threadIdx.x;
    const int lane = tid & 63;
    const int wv = tid >> 6;
    const int m0 = blockIdx.x * 64;
    const int n0 = blockIdx.y * 32;
    const int z  = blockIdx.z;
    const int acol = z << 11;
    const int bcol = z ? Bcol1 : 0;
    const int quad = lane >> 4, mrow = lane & 15;
    const int srow = tid >> 3;            // 0..31
    const int sk8 = (tid & 7) * 8;        // 0..56
    f32x4 acc0 = {0.f, 0.f, 0.f, 0.f};
    f32x4 acc1 = {0.f, 0.f, 0.f, 0.f};
    const unsigned short* Arow0 = A + (size_t)(m0 + srow) * 4096 + acol + sk8;
    const unsigned short* Arow1 = A + (size_t)(m0 + srow + 32) * 4096 + acol + sk8;
    const unsigned short* Brow  = B + (size_t)(n0 + srow) * Bstride + bcol + sk8;
    float4 a0 = *(const float4*)Arow0;
    float4 a1 = *(const float4*)Arow1;
    float4 b0 = *(const float4*)Brow;
    for (int ch = 0; ch < 32; ++ch) {
        __syncthreads();
        *(float4*)&As[srow * 72 + sk8] = a0;
        *(float4*)&As[(srow + 32) * 72 + sk8] = a1;
        *(float4*)&Bs[srow * 72 + sk8] = b0;
        __syncthreads();
        if (ch < 31) {                         // prefetch next chunk
            a0 = *(const float4*)(Arow0 + (ch + 1) * 64);
            a1 = *(const float4*)(Arow1 + (ch + 1) * 64);
            b0 = *(const float4*)(Brow  + (ch + 1) * 64);
        }
        #pragma unroll
        for (int ks = 0; ks < 2; ++ks) {
            bf16x8 af  = *(const bf16x8*)&As[(wv * 16 + mrow) * 72 + ks * 32 + quad * 8];
            bf16x8 bf0 = *(const bf16x8*)&Bs[mrow * 72 + ks * 32 + quad * 8];
            bf16x8 bf1 = *(const bf16x8*)&Bs[(16 + mrow) * 72 + ks * 32 + quad * 8];
            acc0 = __builtin_amdgcn_mfma_f32_16x16x32_bf16(af, bf0, acc0, 0, 0, 0);
            acc1 = __builtin_amdgcn_mfma_f32_16x16x32_bf16(af, bf1, acc1, 0, 0, 0);
        }
    }
    // C/D layout: col = lane&15, row = quad*4 + r
    float* Pz = P + (size_t)z * 524288;
    #pragma unroll
    for (int r = 0; r < 4; ++r) {
        int m = m0 + wv * 16 + quad * 4 + r;
        Pz[m * 512 + n0 + mrow]      = acc0[r];
        Pz[m * 512 + n0 + 16 + mrow] = acc1[r];
    }
}

// ==================================================================
// reduce partials + bias -> com (written over slab 0)
// ==================================================================
__global__ __launch_bounds__(256) void reduce_kernel(float* __restrict__ P,
                                                     const float* __restrict__ bias,
                                                     int SK) {
    int i = blockIdx.x * 256 + threadIdx.x;        // 512K total
    float s = bias[i & 511];
    for (int z = 0; z < SK; ++z) s += P[z * 524288 + i];
    P[i] = s;
}

// ==================================================================
// Fallback fp32 GEMM (only if ws too small for bf16 buffers)
// ==================================================================
__global__ __launch_bounds__(256) void gemm_f32(const float* __restrict__ A,
                                                const float* __restrict__ W,
                                                float* __restrict__ P) {
    __shared__ float Asf[32][128];
    __shared__ float Bsf[32][128];
    const int tid = threadIdx.x;
    const int m0 = blockIdx.x * 128;
    const int n0 = blockIdx.y * 128;
    const int kchunk = 2048 / gridDim.z;
    const int kbase = blockIdx.z * kchunk;
    const int tm = tid >> 4, tn = tid & 15;
    const int srow = tid >> 1;
    const int scol = (tid & 1) * 16;
    float acc[8][8] = {};
    for (int k0 = kbase; k0 < kbase + kchunk; k0 += 32) {
        float4 a[4], w[4];
        const float4* Ap = (const float4*)&A[(m0 + srow) * 2048 + k0 + scol];
        const float4* Wp = (const float4*)&W[(n0 + srow) * 2048 + k0 + scol];
        #pragma unroll
        for (int q = 0; q < 4; ++q) { a[q] = Ap[q]; w[q] = Wp[q]; }
        __syncthreads();
        #pragma unroll
        for (int q = 0; q < 4; ++q) {
            Asf[scol + 4*q + 0][srow] = a[q].x; Asf[scol + 4*q + 1][srow] = a[q].y;
            Asf[scol + 4*q + 2][srow] = a[q].z; Asf[scol + 4*q + 3][srow] = a[q].w;
            Bsf[scol + 4*q + 0][srow] = w[q].x; Bsf[scol + 4*q + 1][srow] = w[q].y;
            Bsf[scol + 4*q + 2][srow] = w[q].z; Bsf[scol + 4*q + 3][srow] = w[q].w;
        }
        __syncthreads();
        #pragma unroll
        for (int kk = 0; kk < 32; ++kk) {
            float4 af0 = *(const float4*)&Asf[kk][tm * 8];
            float4 af1 = *(const float4*)&Asf[kk][tm * 8 + 4];
            float4 bf0 = *(const float4*)&Bsf[kk][tn * 8];
            float4 bf1 = *(const float4*)&Bsf[kk][tn * 8 + 4];
            float av[8] = {af0.x,af0.y,af0.z,af0.w,af1.x,af1.y,af1.z,af1.w};
            float bv[8] = {bf0.x,bf0.y,bf0.z,bf0.w,bf1.x,bf1.y,bf1.z,bf1.w};
            #pragma unroll
            for (int r = 0; r < 8; ++r)
                #pragma unroll
                for (int c = 0; c < 8; ++c)
                    acc[r][c] += av[r] * bv[c];
        }
    }
    float* Pz = P + (size_t)blockIdx.z * 524288;
    #pragma unroll
    for (int r = 0; r < 8; ++r) {
        float4 lo = make_float4(acc[r][0], acc[r][1], acc[r][2], acc[r][3]);
        float4 hi = make_float4(acc[r][4], acc[r][5], acc[r][6], acc[r][7]);
        float* dst = &Pz[(m0 + tm*8 + r) * 512 + n0 + tn*8];
        *(float4*)dst = lo;
        *(float4*)(dst + 4) = hi;
    }
}

// ==================================================================
// Kernel 3: 12-qubit circuit — EXACT R5 structure (78 us measured;
// R6 half-pass and R7 cmt-in-LDS both regressed it).
//   idx = (w1<<11) | (lane<<5) | (w0<<4) | e,  waveId = (w1<<1)|w0
//   V-wires: wire0 -> vm=2, wire7 -> vm=1
//   L-wires: wires1..6 -> lane bits 5..0
//   E-wires: wires8..11 -> e bits 3..0
// ==================================================================
struct CMat { float m00r,m00i,m01r,m01i,m10r,m10i,m11r,m11i; };

__device__ __forceinline__ CMat mk_rot(const float* __restrict__ qp, int l, int w) {
    const float* g = qp + (l * 12 + w) * 3;
    float phi = g[0], th = g[1], om = g[2];
    float st, ct, sa, ca, sb, cb;
    sincosf(0.5f * th, &st, &ct);
    sincosf(0.5f * (phi + om), &sa, &ca);
    sincosf(0.5f * (phi - om), &sb, &cb);
    CMat M;
    M.m00r =  ct * ca; M.m00i = -ct * sa;
    M.m01r = -st * cb; M.m01i = -st * sb;
    M.m10r =  st * cb; M.m10i = -st * sb;
    M.m11r =  ct * ca; M.m11i =  ct * sa;
    return M;
}

template<int W> struct WI {
    static constexpr int kind = (W == 0 || W == 7) ? 2 : ((W >= 1 && W <= 6) ? 1 : 0);
    static constexpr int eb   = (W >= 8) ? (11 - W) : 0;
    static constexpr int lm   = (W >= 1 && W <= 6) ? (1 << (6 - W)) : 0;
    static constexpr int vm   = (W == 0) ? 2 : ((W == 7) ? 1 : 0);
};

__device__ __forceinline__ void exch_put(float* xbuf, int slot,
                                         const float vr[16], const float vi[16]) {
    __syncthreads();
    float4* p = (float4*)xbuf;
    #pragma unroll
    for (int j = 0; j < 8; ++j)
        p[(j << 8) + slot] = make_float4(vr[2*j], vi[2*j], vr[2*j+1], vi[2*j+1]);
    __syncthreads();
}

__device__ __forceinline__ void shfl_perm(float vr[16], float vi[16], int src) {
    #pragma unroll
    for (int e = 0; e < 16; ++e) {
        vr[e] = __shfl(vr[e], src, 64);
        vi[e] = __shfl(vi[e], src, 64);
    }
}

template<int EB>
__device__ __forceinline__ void rot_local(float vr[16], float vi[16], const CMat& M) {
    #pragma unroll
    for (int e = 0; e < 16; ++e) if (!(e & (1 << EB))) {
        const int e1 = e | (1 << EB);
        float x0r = vr[e],  x0i = vi[e];
        float x1r = vr[e1], x1i = vi[e1];
        vr[e]  = M.m00r*x0r - M.m00i*x0i + M.m01r*x1r - M.m01i*x1i;
        vi[e]  = M.m00r*x0i + M.m00i*x0r + M.m01r*x1i + M.m01i*x1r;
        vr[e1] = M.m10r*x0r - M.m10i*x0i + M.m11r*x1r - M.m11i*x1i;
        vi[e1] = M.m10r*x0i + M.m10i*x0r + M.m11r*x1i + M.m11i*x1r;
    }
}

template<int LM>
__device__ __forceinline__ void rot_lane(float vr[16], float vi[16], int lane, const CMat& M) {
    const bool hi = lane & LM;
    const float Ar = hi ? M.m11r : M.m00r, Ai = hi ? M.m11i : M.m00i;
    const float Br = hi ? M.m10r : M.m01r, Bi = hi ? M.m10i : M.m01i;
    #pragma unroll
    for (int e = 0; e < 16; ++e) {
        float pr = __shfl_xor(vr[e], LM, 64);
        float pi = __shfl_xor(vi[e], LM, 64);
        float orr = vr[e], oi = vi[e];
        vr[e] = Ar*orr - Ai*oi + Br*pr - Bi*pi;
        vi[e] = Ar*oi + Ai*orr + Br*pi + Bi*pr;
    }
}

template<int VM>
__device__ __forceinline__ void rot_wave(float vr[16], float vi[16], float* xbuf,
                                         int waveId, int lane, const CMat& M) {
    exch_put(xbuf, (waveId << 6) + lane, vr, vi);
    const float4* p = (const float4*)xbuf;
    const int ps = ((waveId ^ VM) << 6) + lane;
    const bool hi = waveId & VM;
    const float Ar = hi ? M.m11r : M.m00r, Ai = hi ? M.m11i : M.m00i;
    const float Br = hi ? M.m10r : M.m01r, Bi = hi ? M.m10i : M.m01i;
    #pragma unroll
    for (int j = 0; j < 8; ++j) {
        float4 q = p[(j << 8) + ps];
        const int e0 = 2*j, e1 = 2*j + 1;
        float r0 = vr[e0], i0 = vi[e0], r1 = vr[e1], i1 = vi[e1];
        vr[e0] = Ar*r0 - Ai*i0 + Br*q.x - Bi*q.y;
        vi[e0] = Ar*i0 + Ai*r0 + Br*q.y + Bi*q.x;
        vr[e1] = Ar*r1 - Ai*i1 + Br*q.z - Bi*q.w;
        vi[e1] = Ar*i1 + Ai*r1 + Br*q.w + Bi*q.z;
    }
}

template<int W>
__device__ __forceinline__ void rot_wire(float vr[16], float vi[16], float* xbuf,
                                         int waveId, int lane, const CMat& M) {
    if constexpr (WI<W>::kind == 0)      rot_local<WI<W>::eb>(vr, vi, M);
    else if constexpr (WI<W>::kind == 1) rot_lane<WI<W>::lm>(vr, vi, lane, M);
    else                                 rot_wave<WI<W>::vm>(vr, vi, xbuf, waveId, lane, M);
}

template<int C, int T>
__device__ __forceinline__ void cnot(float vr[16], float vi[16], float* xbuf,
                                     int waveId, int lane) {
    constexpr int ck = WI<C>::kind, tk = WI<T>::kind;
    if constexpr (ck == 0 && tk == 0) {
        constexpr int cb = 1 << WI<C>::eb, tb = 1 << WI<T>::eb;
        #pragma unroll
        for (int e = 0; e < 16; ++e) if ((e & cb) && !(e & tb)) {
            const int e1 = e | tb;
            float t = vr[e]; vr[e] = vr[e1]; vr[e1] = t;
            t = vi[e]; vi[e] = vi[e1]; vi[e1] = t;
        }
    } else if constexpr (ck == 0 && tk == 1) {
        constexpr int cb = 1 << WI<C>::eb, tm = WI<T>::lm;
        #pragma unroll
        for (int e = 0; e < 16; ++e) if (e & cb) {
            vr[e] = __shfl_xor(vr[e], tm, 64);
            vi[e] = __shfl_xor(vi[e], tm, 64);
        }
    } else if constexpr (ck == 0 && tk == 2) {
        constexpr int cb = 1 << WI<C>::eb, vm = WI<T>::vm;
        exch_put(xbuf, (waveId << 6) + lane, vr, vi);
        const float4* p = (const float4*)xbuf;
        const int ps = ((waveId ^ vm) << 6) + lane;
        #pragma unroll
        for (int j = 0; j < 8; ++j) {
            if ((((2*j) & cb) != 0) || (((2*j+1) & cb) != 0)) {
                float4 q = p[(j << 8) + ps];
                if (((2*j) & cb) != 0)   { vr[2*j]   = q.x; vi[2*j]   = q.y; }
                if (((2*j+1) & cb) != 0) { vr[2*j+1] = q.z; vi[2*j+1] = q.w; }
            }
        }
    } else if constexpr (ck == 1 && tk == 0) {
        constexpr int cm = WI<C>::lm, tb = 1 << WI<T>::eb;
        const bool cc = lane & cm;
        #pragma unroll
        for (int e = 0; e < 16; ++e) if (!(e & tb)) {
            const int e1 = e | tb;
            float a = vr[e], bb = vr[e1];
            vr[e] = cc ? bb : a; vr[e1] = cc ? a : bb;
            a = vi[e]; bb = vi[e1];
            vi[e] = cc ? bb : a; vi[e1] = cc ? a : bb;
        }
    } else if constexpr (ck == 1 && tk == 1) {
        constexpr int cm = WI<C>::lm, tm = WI<T>::lm;
        const int src = (lane & cm) ? (lane ^ tm) : lane;
        shfl_perm(vr, vi, src);
    } else if constexpr (ck == 1 && tk == 2) {
        constexpr int cm = WI<C>::lm, vm = WI<T>::vm;
        exch_put(xbuf, (waveId << 6) + lane, vr, vi);
        const float4* p = (const float4*)xbuf;
        const int ps = ((waveId ^ vm) << 6) + lane;
        const bool take = lane & cm;
        #pragma unroll
        for (int j = 0; j < 8; ++j) {
            float4 q = p[(j << 8) + ps];
            vr[2*j]   = take ? q.x : vr[2*j];   vi[2*j]   = take ? q.y : vi[2*j];
            vr[2*j+1] = take ? q.z : vr[2*j+1]; vi[2*j+1] = take ? q.w : vi[2*j+1];
        }
    } else if constexpr (ck == 2 && tk == 0) {
        constexpr int vm = WI<C>::vm, tb = 1 << WI<T>::eb;
        if (waveId & vm) {
            #pragma unroll
            for (int e = 0; e < 16; ++e) if (!(e & tb)) {
                const int e1 = e | tb;
                float t = vr[e]; vr[e] = vr[e1]; vr[e1] = t;
                t = vi[e]; vi[e] = vi[e1]; vi[e1] = t;
            }
        }
    } else {
        constexpr int vm = WI<C>::vm, tm = WI<T>::lm;
        if (waveId & vm) {
            #pragma unroll
            for (int e = 0; e < 16; ++e) {
                vr[e] = __shfl_xor(vr[e], tm, 64);
                vi[e] = __shfl_xor(vi[e], tm, 64);
            }
        }
    }
}

template<int W>
__device__ __forceinline__ void h_wire(float vr[16], float vi[16], float* xbuf,
                                       int waveId, int lane) {
    if constexpr (WI<W>::kind == 0) {
        constexpr int tb = 1 << WI<W>::eb;
        #pragma unroll
        for (int e = 0; e < 16; ++e) if (!(e & tb)) {
            const int e1 = e | tb;
            float x0 = vr[e], x1 = vr[e1];
            vr[e] = (x0 + x1) * RS2f; vr[e1] = (x0 - x1) * RS2f;
            x0 = vi[e]; x1 = vi[e1];
            vi[e] = (x0 + x1) * RS2f; vi[e1] = (x0 - x1) * RS2f;
        }
    } else if constexpr (WI<W>::kind == 1) {
        constexpr int m = WI<W>::lm;
        const float sgn = (lane & m) ? -RS2f : RS2f;
        #pragma unroll
        for (int e = 0; e < 16; ++e) {
            float pr = __shfl_xor(vr[e], m, 64);
            float pi = __shfl_xor(vi[e], m, 64);
            vr[e] = pr * RS2f + vr[e] * sgn;
            vi[e] = pi * RS2f + vi[e] * sgn;
        }
    } else {
        constexpr int vm = WI<W>::vm;
        exch_put(xbuf, (waveId << 6) + lane, vr, vi);
        const float4* p = (const float4*)xbuf;
        const int ps = ((waveId ^ vm) << 6) + lane;
        const float sgn = (waveId & vm) ? -RS2f : RS2f;
        #pragma unroll
        for (int j = 0; j < 8; ++j) {
            float4 q = p[(j << 8) + ps];
            vr[2*j]   = q.x * RS2f + vr[2*j]   * sgn;
            vi[2*j]   = q.y * RS2f + vi[2*j]   * sgn;
            vr[2*j+1] = q.z * RS2f + vr[2*j+1] * sgn;
            vi[2*j+1] = q.w * RS2f + vi[2*j+1] * sgn;
        }
    }
}

__global__ __launch_bounds__(256) void circuit_kernel(const float* __restrict__ com,
                                                      const float* __restrict__ xf,
                                                      const float* __restrict__ qp,
                                                      float* __restrict__ out) {
    __shared__ float xbuf[8192];         // 32 KB exchange buffer
    __shared__ float ang[2048];          // 8 KB: com row, later xf row
    const int tid = threadIdx.x;
    const int lane = tid & 63;
    const int waveId = tid >> 6;
    const int b = blockIdx.x;

    if (tid < 128) ((float4*)ang)[tid] = ((const float4*)(com + b * 512))[tid];
    __syncthreads();

    float vr[16], vi[16];
    #pragma unroll
    for (int e = 0; e < 16; ++e) { vr[e] = 0.0f; vi[e] = 0.0f; }

    // FRQI-1 closed form: amp nonzero where wires10,11 = 0 -> e in {0,4,8,12}
    const float K9 = 0.044194173824159216f;   // 2^-4.5
    #pragma unroll
    for (int m = 0; m < 4; ++m) {
        int j = (lane << 3) | ((waveId & 1) << 2) | m;
        int rj = (int)(__brev((unsigned)j) >> 23);
        float s, c;
        sincosf(0.5f * ang[rj], &s, &c);
        vr[m << 2] = K9 * ((waveId & 2) ? s : c);
    }

    #pragma unroll 1
    for (int l = 0; l < 2; ++l) {
        { CMat M = mk_rot(qp, l, 0);  rot_wire<0 >(vr, vi, xbuf, waveId, lane, M); }
        { CMat M = mk_rot(qp, l, 1);  rot_wire<1 >(vr, vi, xbuf, waveId, lane, M); }
        { CMat M = mk_rot(qp, l, 2);  rot_wire<2 >(vr, vi, xbuf, waveId, lane, M); }
        { CMat M = mk_rot(qp, l, 3);  rot_wire<3 >(vr, vi, xbuf, waveId, lane, M); }
        { CMat M = mk_rot(qp, l, 4);  rot_wire<4 >(vr, vi, xbuf, waveId, lane, M); }
        { CMat M = mk_rot(qp, l, 5);  rot_wire<5 >(vr, vi, xbuf, waveId, lane, M); }
        { CMat M = mk_rot(qp, l, 6);  rot_wire<6 >(vr, vi, xbuf, waveId, lane, M); }
        { CMat M = mk_rot(qp, l, 7);  rot_wire<7 >(vr, vi, xbuf, waveId, lane, M); }
        { CMat M = mk_rot(qp, l, 8);  rot_wire<8 >(vr, vi, xbuf, waveId, lane, M); }
        { CMat M = mk_rot(qp, l, 9);  rot_wire<9 >(vr, vi, xbuf, waveId, lane, M); }
        { CMat M = mk_rot(qp, l, 10); rot_wire<10>(vr, vi, xbuf, waveId, lane, M); }
        { CMat M = mk_rot(qp, l, 11); rot_wire<11>(vr, vi, xbuf, waveId, lane, M); }
        if (l == 0) {                 // r = 1
            int j = lane;
            j ^= (j & 2)  ? 1  : 0;           // C(5,6)
            j ^= (j & 4)  ? 2  : 0;           // C(4,5)
            j ^= (j & 8)  ? 4  : 0;           // C(3,4)
            j ^= (j & 16) ? 8  : 0;           // C(2,3)
            j ^= (j & 32) ? 16 : 0;           // C(1,2)
            j ^= (waveId & 2) ? 32 : 0;       // C(0,1)
            shfl_perm(vr, vi, j);
            cnot<6,7>(vr,vi,xbuf,waveId,lane);   cnot<7,8>(vr,vi,xbuf,waveId,lane);
            cnot<8,9>(vr,vi,xbuf,waveId,lane);   cnot<9,10>(vr,vi,xbuf,waveId,lane);
            cnot<10,11>(vr,vi,xbuf,waveId,lane); cnot<11,0>(vr,vi,xbuf,waveId,lane);
        } else {                      // r = 2
            int j = lane;
            j ^= (j & 4)  ? 1  : 0;           // C(4,6)
            j ^= (j & 8)  ? 2  : 0;           // C(3,5)
            j ^= (j & 16) ? 4  : 0;           // C(2,4)
            j ^= (j & 32) ? 8  : 0;           // C(1,3)
            j ^= (waveId & 2) ? 16 : 0;       // C(0,2)
            shfl_perm(vr, vi, j);
            cnot<5,7>(vr,vi,xbuf,waveId,lane);   cnot<6,8>(vr,vi,xbuf,waveId,lane);
            cnot<7,9>(vr,vi,xbuf,waveId,lane);   cnot<8,10>(vr,vi,xbuf,waveId,lane);
            cnot<9,11>(vr,vi,xbuf,waveId,lane);  cnot<10,0>(vr,vi,xbuf,waveId,lane);
            cnot<11,1>(vr,vi,xbuf,waveId,lane);
        }
    }

    // FRQI-2 Hadamards on wires 1..11
    h_wire<1>(vr,vi,xbuf,waveId,lane);  h_wire<2>(vr,vi,xbuf,waveId,lane);
    h_wire<3>(vr,vi,xbuf,waveId,lane);  h_wire<4>(vr,vi,xbuf,waveId,lane);
    h_wire<5>(vr,vi,xbuf,waveId,lane);  h_wire<6>(vr,vi,xbuf,waveId,lane);
    h_wire<7>(vr,vi,xbuf,waveId,lane);  h_wire<8>(vr,vi,xbuf,waveId,lane);
    h_wire<9>(vr,vi,xbuf,waveId,lane);  h_wire<10>(vr,vi,xbuf,waveId,lane);
    h_wire<11>(vr,vi,xbuf,waveId,lane);

    // stage xf row
    {
        const float4* x4 = (const float4*)(xf + b * 2048);
        ((float4*)ang)[tid]       = x4[tid];
        ((float4*)ang)[tid + 256] = x4[tid + 256];
    }
    __syncthreads();

    // fused UC-RY(img) on wire0 (vm=2) + Z(0) expectation
    exch_put(xbuf, (waveId << 6) + lane, vr, vi);
    {
        const float4* p = (const float4*)xbuf;
        const int ps = ((waveId ^ 2) << 6) + lane;
        const bool hi = waveId & 2;
        float acc = 0.0f;
        #pragma unroll
        for (int j = 0; j < 8; ++j) {
            float4 q = p[(j << 8) + ps];
            #pragma unroll
            for (int h = 0; h < 2; ++h) {
                const int e = 2*j + h;
                const float prr = h ? q.z : q.x;
                const float pii = h ? q.w : q.y;
                int v = (lane << 5) | ((waveId & 1) << 4) | e;
                int rv = (int)(__brev((unsigned)v) >> 21);
                float s, c;
                sincosf(0.5f * ang[rv], &s, &c);
                float nr = hi ? (s*prr + c*vr[e]) : (c*vr[e] - s*prr);
                float ni = hi ? (s*pii + c*vi[e]) : (c*vi[e] - s*pii);
                acc += nr*nr + ni*ni;
            }
        }
        if (!hi) acc = -acc;
        #pragma unroll
        for (int off = 32; off > 0; off >>= 1) acc += __shfl_down(acc, off, 64);
        __syncthreads();
        if (lane == 0) xbuf[waveId] = acc;
        __syncthreads();
        if (tid == 0) out[b] = xbuf[0] + xbuf[1] + xbuf[2] + xbuf[3];
    }
}

extern "C" void kernel_launch(void* const* d_in, const int* in_sizes, int n_in,
                              void* d_out, int out_size, void* d_ws, size_t ws_size,
                              hipStream_t stream) {
    const float* x    = (const float*)d_in[0];   // (1024,2048)
    const float* W    = (const float*)d_in[1];   // (512,2048)
    const float* bias = (const float*)d_in[2];   // (512,)
    const float* qp   = (const float*)d_in[3];   // (2,12,3)
    float* out = (float*)d_out;                  // (1024,)

    const size_t MB = 1024ull * 1024;
    if (ws_size >= 16 * MB) {
        // xc [xh|xl] 8MB | wc [wh|wl] 4MB | P0 2MB | P1 2MB
        unsigned short* xc = (unsigned short*)d_ws;
        unsigned short* wc = (unsigned short*)((char*)d_ws + 8 * MB);
        float* P = (float*)((char*)d_ws + 12 * MB);
        split_kernel<<<2048, 256, 0, stream>>>(x, xc);
        split_kernel<<<1024, 256, 0, stream>>>(W, wc);
        dim3 g(16, 16, 2);
        gemm_mfma<<<g, 256, 0, stream>>>(xc, wc, 4096, 2048, P);  // z0: xh.wh, z1: xl.wl
        reduce_kernel<<<2048, 256, 0, stream>>>(P, bias, 2);
        circuit_kernel<<<1024, 256, 0, stream>>>(P, x, qp, out);
    } else if (ws_size >= 14 * MB) {
        // xc [xh|xl] 8MB | wh 2MB | P0 2MB | P1 2MB   (B shared across z)
        unsigned short* xc = (unsigned short*)d_ws;
        unsigned short* wh = (unsigned short*)((char*)d_ws + 8 * MB);
        float* P = (float*)((char*)d_ws + 10 * MB);
        split_kernel<<<2048, 256, 0, stream>>>(x, xc);
        conv_hi<<<1024, 256, 0, stream>>>(W, wh);
        dim3 g(16, 16, 2);
        gemm_mfma<<<g, 256, 0, stream>>>(xc, wh, 2048, 0, P);     // z0: xh.wh, z1: xl.wh
        reduce_kernel<<<2048, 256, 0, stream>>>(P, bias, 2);
        circuit_kernel<<<1024, 256, 0, stream>>>(P, x, qp, out);
    } else {
        // fallback: fp32 split-K partials + reduce (R5 path)
        float* P = (float*)d_ws;
        const size_t slab = 1024 * 512 * sizeof(float);
        int SK = 1;
        if      (ws_size >= 16 * slab) SK = 16;
        else if (ws_size >=  8 * slab) SK = 8;
        else if (ws_size >=  4 * slab) SK = 4;
        else if (ws_size >=  2 * slab) SK = 2;
        dim3 ggrid(8, 4, SK);
        gemm_f32<<<ggrid, 256, 0, stream>>>(x, W, P);
        reduce_kernel<<<2048, 256, 0, stream>>>(P, bias, SK);
        circuit_kernel<<<1024, 256, 0, stream>>>(P, x, qp, out);
    }
}